// Round 3
// baseline (307.395 us; speedup 1.0000x reference)
//
#include <hip/hip_runtime.h>
#include <hip/hip_bf16.h>

#define K1 195
#define K1P 224
#define K2 131
#define K2B 136   // structB padded cols (272 B rows, 16B-aligned)
#define K2P 160   // MFMA K extent for GEMM2
#define OC 256
#define BM 64
#define S1 232    // LDS row stride A1 (bf16 elems): 464 B
#define S2 168    // LDS row stride A2 (bf16 elems): 336 B

typedef __attribute__((ext_vector_type(4))) float f32x4;
typedef __attribute__((ext_vector_type(8))) short bf16x8;

__device__ __forceinline__ float b2f(short x) {
    return __uint_as_float(((unsigned)(unsigned short)x) << 16);
}
__device__ __forceinline__ short f2b(float x) {
    __hip_bfloat16 h = __float2bfloat16(x);
    return *reinterpret_cast<short*>(&h);
}

// ---- prep: weights -> bf16 (zero-padded K), structural -> bf16 [N,136] ----
__global__ void prep_kernel(const float* __restrict__ Wc, const float* __restrict__ Wa,
                            const float* __restrict__ structural,
                            __hip_bfloat16* __restrict__ WcP, __hip_bfloat16* __restrict__ WaP,
                            __hip_bfloat16* __restrict__ structB, int n) {
    int t = blockIdx.x * blockDim.x + threadIdx.x;
    const int t1 = OC * K1P;
    const int t2 = OC * K2P;
    if (t < t1) {
        int oc = t / K1P, k = t - oc * K1P;
        WcP[t] = __float2bfloat16((k < K1) ? Wc[oc * K1 + k] : 0.0f);
    } else if (t < t1 + t2) {
        int u = t - t1;
        int oc = u / K2P, k = u - oc * K2P;
        WaP[u] = __float2bfloat16((k < K2) ? Wa[oc * K2 + k] : 0.0f);
    } else {
        int u = t - (t1 + t2);
        if (u < n * K2B) {
            int r = u / K2B, k = u - r * K2B;
            structB[u] = __float2bfloat16((k < K2) ? structural[(size_t)r * K2 + k] : 0.0f);
        }
    }
}

// ---- out1 = concat(spatial, structural) x Wc^T + bc ----
__global__ __launch_bounds__(256) void out1_kernel(
        const float* __restrict__ spatial,
        const float* __restrict__ structural,
        const __hip_bfloat16* __restrict__ WcP,
        const float* __restrict__ bc,
        float* __restrict__ out1, int n) {
    __shared__ __hip_bfloat16 A1[BM][S1];

    const int t = threadIdx.x;
    const int r0 = blockIdx.x * BM;

    // zero-pad cols [195,224)
    for (int e = t; e < BM * (K1P - K1); e += 256) {
        int r = e / (K1P - K1);
        int k = K1 + (e - r * (K1P - K1));
        A1[r][k] = __float2bfloat16(0.0f);
    }

    // spatial -> A1[:,0:64] (aligned float4 streaming)
    {
        int r = t >> 2;
        int c0 = (t & 3) * 16;
        const f32x4* src = (const f32x4*)(spatial + (size_t)(r0 + r) * 64 + c0);
        #pragma unroll
        for (int i = 0; i < 4; ++i) {
            f32x4 v = src[i];
            #pragma unroll
            for (int j = 0; j < 4; ++j)
                A1[r][c0 + i * 4 + j] = __float2bfloat16(v[j]);
        }
    }

    // structural rows r0..r0+63 are CONTIGUOUS: flat float4 copy (16B-aligned base)
    {
        const float* sbase = structural + (size_t)r0 * K2;
        const int nf4 = (BM * K2) / 4;  // 2096
        #pragma unroll 3
        for (int f = t; f < nf4; f += 256) {
            f32x4 v = *(const f32x4*)(sbase + (size_t)f * 4);
            int g = f * 4;
            #pragma unroll
            for (int j = 0; j < 4; ++j) {
                int gg = g + j;
                int r = gg / K2;
                int k = gg - r * K2;
                A1[r][64 + k] = __float2bfloat16(v[j]);
            }
        }
    }
    __syncthreads();

    const int wid  = t >> 6;
    const int lane = t & 63;
    const int lr   = lane & 15;
    const int lkc  = lane >> 4;
    const int colBase = wid * 64;

    f32x4 acc[4][4];
    #pragma unroll
    for (int i = 0; i < 4; ++i)
        #pragma unroll
        for (int j = 0; j < 4; ++j)
            acc[i][j] = (f32x4){0.f, 0.f, 0.f, 0.f};

    #pragma unroll
    for (int ks = 0; ks < K1P; ks += 32) {
        bf16x8 a[4], b[4];
        #pragma unroll
        for (int rt = 0; rt < 4; ++rt)
            a[rt] = *(const bf16x8*)&A1[rt * 16 + lr][ks + lkc * 8];
        #pragma unroll
        for (int ct = 0; ct < 4; ++ct) {
            int oc = colBase + ct * 16 + lr;
            b[ct] = *(const bf16x8*)(WcP + (size_t)oc * K1P + ks + lkc * 8);
        }
        #pragma unroll
        for (int rt = 0; rt < 4; ++rt)
            #pragma unroll
            for (int ct = 0; ct < 4; ++ct)
                acc[rt][ct] = __builtin_amdgcn_mfma_f32_16x16x32_bf16(a[rt], b[ct], acc[rt][ct], 0, 0, 0);
    }

    #pragma unroll
    for (int ct = 0; ct < 4; ++ct) {
        int col = colBase + ct * 16 + lr;
        float bias = bc[col];
        #pragma unroll
        for (int rt = 0; rt < 4; ++rt) {
            #pragma unroll
            for (int j = 0; j < 4; ++j) {
                int row = r0 + rt * 16 + lkc * 4 + j;
                if (row < n)
                    out1[(size_t)row * OC + col] = acc[rt][ct][j] + bias;
            }
        }
    }
}

// ---- out2 = 0.25*(structural + sum of 3 gathered rows) x Wa^T + ba ----
__global__ __launch_bounds__(256) void out2_kernel(
        const __hip_bfloat16* __restrict__ structB,
        const int* __restrict__ neighbour,
        const __hip_bfloat16* __restrict__ WaP,
        const float* __restrict__ ba,
        float* __restrict__ out2, int n) {
    __shared__ __hip_bfloat16 A2[BM][S2];
    __shared__ int nidx[BM * 3];

    const int t = threadIdx.x;
    const int r0 = blockIdx.x * BM;

    if (t < BM * 3)
        nidx[t] = neighbour[(size_t)r0 * 3 + t];

    // zero-fill cols [136,168) — disjoint from data region, no extra barrier needed
    {
        int r = t >> 2, c = K2B + (t & 3) * 8;
        *(bf16x8*)&A2[r][c] = (bf16x8){0, 0, 0, 0, 0, 0, 0, 0};
    }
    __syncthreads();  // nidx ready

    // gather+average: 64 rows x 17 chunks of 8 bf16, dwordx4 loads
    #pragma unroll 2
    for (int i = 0; i < 5; ++i) {
        int u = t + i * 256;
        if (u < BM * 17) {
            int r = u / 17;
            int c = u - r * 17;
            int rr = r0 + r;
            bf16x8 vs = *(const bf16x8*)(structB + (size_t)rr * K2B + c * 8);
            int n0 = nidx[r * 3 + 0];
            int n1 = nidx[r * 3 + 1];
            int n2 = nidx[r * 3 + 2];
            bf16x8 v0 = *(const bf16x8*)(structB + (size_t)n0 * K2B + c * 8);
            bf16x8 v1 = *(const bf16x8*)(structB + (size_t)n1 * K2B + c * 8);
            bf16x8 v2 = *(const bf16x8*)(structB + (size_t)n2 * K2B + c * 8);
            bf16x8 o;
            #pragma unroll
            for (int j = 0; j < 8; ++j) {
                float a = b2f(vs[j]) + b2f(v0[j]) + b2f(v1[j]) + b2f(v2[j]);
                o[j] = f2b(a * 0.25f);
            }
            *(bf16x8*)&A2[r][c * 8] = o;
        }
    }
    __syncthreads();

    const int wid  = t >> 6;
    const int lane = t & 63;
    const int lr   = lane & 15;
    const int lkc  = lane >> 4;
    const int colBase = wid * 64;

    f32x4 acc[4][4];
    #pragma unroll
    for (int i = 0; i < 4; ++i)
        #pragma unroll
        for (int j = 0; j < 4; ++j)
            acc[i][j] = (f32x4){0.f, 0.f, 0.f, 0.f};

    #pragma unroll
    for (int ks = 0; ks < K2P; ks += 32) {
        bf16x8 a[4], b[4];
        #pragma unroll
        for (int rt = 0; rt < 4; ++rt)
            a[rt] = *(const bf16x8*)&A2[rt * 16 + lr][ks + lkc * 8];
        #pragma unroll
        for (int ct = 0; ct < 4; ++ct) {
            int oc = colBase + ct * 16 + lr;
            b[ct] = *(const bf16x8*)(WaP + (size_t)oc * K2P + ks + lkc * 8);
        }
        #pragma unroll
        for (int rt = 0; rt < 4; ++rt)
            #pragma unroll
            for (int ct = 0; ct < 4; ++ct)
                acc[rt][ct] = __builtin_amdgcn_mfma_f32_16x16x32_bf16(a[rt], b[ct], acc[rt][ct], 0, 0, 0);
    }

    #pragma unroll
    for (int ct = 0; ct < 4; ++ct) {
        int col = colBase + ct * 16 + lr;
        float bias = ba[col];
        #pragma unroll
        for (int rt = 0; rt < 4; ++rt) {
            #pragma unroll
            for (int j = 0; j < 4; ++j) {
                int row = r0 + rt * 16 + lkc * 4 + j;
                if (row < n)
                    out2[(size_t)row * OC + col] = acc[rt][ct][j] + bias;
            }
        }
    }
}

extern "C" void kernel_launch(void* const* d_in, const int* in_sizes, int n_in,
                              void* d_out, int out_size, void* d_ws, size_t ws_size,
                              hipStream_t stream) {
    const float* spatial    = (const float*)d_in[0];
    const float* structural = (const float*)d_in[1];
    const int*   neighbour  = (const int*)d_in[2];
    const float* Wc = (const float*)d_in[3];
    const float* bc = (const float*)d_in[4];
    const float* Wa = (const float*)d_in[5];
    const float* ba = (const float*)d_in[6];

    const int n = in_sizes[0] / 64;  // 200000

    float* out1 = (float*)d_out;
    float* out2 = out1 + (size_t)n * OC;

    __hip_bfloat16* WcP = (__hip_bfloat16*)d_ws;
    __hip_bfloat16* WaP = WcP + OC * K1P;

    const size_t wbytes = (size_t)(OC * K1P + OC * K2P) * sizeof(__hip_bfloat16);
    const size_t sbytes = (size_t)n * K2B * sizeof(__hip_bfloat16);

    // structB: in ws if it fits, else in the out1 region of d_out (safe:
    // prep -> out2 (reads structB) -> out1 (overwrites region) is stream-ordered)
    __hip_bfloat16* structB;
    if (ws_size >= wbytes + sbytes)
        structB = (__hip_bfloat16*)((char*)d_ws + wbytes);
    else
        structB = (__hip_bfloat16*)d_out;

    {
        const long total = (long)(OC * K1P + OC * K2P) + (long)n * K2B;
        const int grid = (int)((total + 255) / 256);
        prep_kernel<<<grid, 256, 0, stream>>>(Wc, Wa, structural, WcP, WaP, structB, n);
    }
    {
        const int grid = (n + BM - 1) / BM;  // 3125
        out2_kernel<<<grid, 256, 0, stream>>>(structB, neighbour, WaP, ba, out2, n);
        out1_kernel<<<grid, 256, 0, stream>>>(spatial, structural, WcP, bc, out1, n);
    }
}